// Round 1
// baseline (145.887 us; speedup 1.0000x reference)
//
#include <hip/hip_runtime.h>
#include <math.h>

// Reference reduction insight: all graph edge weights are 1.0 so
// mean_w = where(deg>0, deg/deg, 1.0) == 1.0 everywhere => attn == q_out.
// The 8192x8192 fidelity matrix is a mathematical no-op. We compute only:
//   out = colsum( tanh( relu( relu(S@W1+b1)@W2+b2 )@Wq+bq ) ) @ Wh + bh

#define N_ROWS 8192
#define F_IN   512
#define H_DIM  256
#define W_DIM  64

#define BM 64
#define BN 64
#define BK 16
#define LDS_A (BM + 4)   // pad: stride 68 keeps 16B alignment, breaks 4-way bank conflicts
#define LDS_B (BN + 4)

// C[M,N] = relu(A[M,K] @ W[K,N] + bias[N]); M,K,N multiples of tile dims.
__global__ __launch_bounds__(256) void gemm_bias_relu(
    const float* __restrict__ A, const float* __restrict__ W,
    const float* __restrict__ bias, float* __restrict__ C,
    int K, int N)
{
    __shared__ float As[BK * LDS_A];
    __shared__ float Bs[BK * LDS_B];
    const int t  = threadIdx.x;
    const int tx = t & 15;          // 16 col groups
    const int ty = t >> 4;          // 16 row groups
    const int row0 = blockIdx.x * BM;
    const int col0 = blockIdx.y * BN;

    const int la_row = t >> 2;          // 0..63
    const int la_k   = (t & 3) << 2;    // 0,4,8,12
    const int lb_row = t >> 4;          // 0..15
    const int lb_col = (t & 15) << 2;   // 0..60

    float acc[4][4] = {};

    for (int k0 = 0; k0 < K; k0 += BK) {
        float4 av = *(const float4*)(A + (size_t)(row0 + la_row) * K + (k0 + la_k));
        As[(la_k + 0) * LDS_A + la_row] = av.x;
        As[(la_k + 1) * LDS_A + la_row] = av.y;
        As[(la_k + 2) * LDS_A + la_row] = av.z;
        As[(la_k + 3) * LDS_A + la_row] = av.w;
        *(float4*)(Bs + lb_row * LDS_B + lb_col) =
            *(const float4*)(W + (size_t)(k0 + lb_row) * N + (col0 + lb_col));
        __syncthreads();
        #pragma unroll
        for (int k = 0; k < BK; ++k) {
            float4 a = *(const float4*)(As + k * LDS_A + (ty << 2));
            float4 b = *(const float4*)(Bs + k * LDS_B + (tx << 2));
            float ar[4] = {a.x, a.y, a.z, a.w};
            float br[4] = {b.x, b.y, b.z, b.w};
            #pragma unroll
            for (int i = 0; i < 4; ++i)
                #pragma unroll
                for (int j = 0; j < 4; ++j)
                    acc[i][j] = fmaf(ar[i], br[j], acc[i][j]);
        }
        __syncthreads();
    }

    #pragma unroll
    for (int i = 0; i < 4; ++i) {
        const size_t r = (size_t)(row0 + (ty << 2) + i);
        #pragma unroll
        for (int j = 0; j < 4; ++j) {
            const int c = col0 + (tx << 2) + j;
            C[r * N + c] = fmaxf(acc[i][j] + bias[c], 0.0f);
        }
    }
}

// agg[64] += colsum over this block's 64 rows of tanh(A@Wq + bq). Never
// materializes q_out. Grid: (N_ROWS/BM, 1). K=H_DIM=256, N=W_DIM=64.
__global__ __launch_bounds__(256) void gemm_tanh_colsum(
    const float* __restrict__ A, const float* __restrict__ W,
    const float* __restrict__ bias, float* __restrict__ agg)
{
    const int K = H_DIM, N = W_DIM;
    __shared__ float As[BK * LDS_A];
    __shared__ float Bs[BK * LDS_B];
    const int t  = threadIdx.x;
    const int tx = t & 15;
    const int ty = t >> 4;
    const int row0 = blockIdx.x * BM;

    const int la_row = t >> 2;
    const int la_k   = (t & 3) << 2;
    const int lb_row = t >> 4;
    const int lb_col = (t & 15) << 2;

    float acc[4][4] = {};

    for (int k0 = 0; k0 < K; k0 += BK) {
        float4 av = *(const float4*)(A + (size_t)(row0 + la_row) * K + (k0 + la_k));
        As[(la_k + 0) * LDS_A + la_row] = av.x;
        As[(la_k + 1) * LDS_A + la_row] = av.y;
        As[(la_k + 2) * LDS_A + la_row] = av.z;
        As[(la_k + 3) * LDS_A + la_row] = av.w;
        *(float4*)(Bs + lb_row * LDS_B + lb_col) =
            *(const float4*)(W + (size_t)(k0 + lb_row) * N + lb_col);
        __syncthreads();
        #pragma unroll
        for (int k = 0; k < BK; ++k) {
            float4 a = *(const float4*)(As + k * LDS_A + (ty << 2));
            float4 b = *(const float4*)(Bs + k * LDS_B + (tx << 2));
            float ar[4] = {a.x, a.y, a.z, a.w};
            float br[4] = {b.x, b.y, b.z, b.w};
            #pragma unroll
            for (int i = 0; i < 4; ++i)
                #pragma unroll
                for (int j = 0; j < 4; ++j)
                    acc[i][j] = fmaf(ar[i], br[j], acc[i][j]);
        }
        __syncthreads();
    }

    // per-thread column partial sums of tanh(acc + bias)
    float csum[4];
    #pragma unroll
    for (int j = 0; j < 4; ++j) {
        const int c = (tx << 2) + j;
        float s = 0.f;
        #pragma unroll
        for (int i = 0; i < 4; ++i)
            s += tanhf(acc[i][j] + bias[c]);
        csum[j] = s;
    }
    __syncthreads();                 // everyone past the K loop; As reusable
    float* red = As;                 // 16 x 64 scratch (needs 1024 <= 1088)
    #pragma unroll
    for (int j = 0; j < 4; ++j)
        red[ty * 64 + (tx << 2) + j] = csum[j];
    __syncthreads();
    if (t < 64) {
        float s = 0.f;
        #pragma unroll
        for (int r = 0; r < 16; ++r) s += red[r * 64 + t];
        atomicAdd(&agg[t], s);       // 128 blocks x 64 cols = 8192 atomics total
    }
}

// out[0] = dot(agg, Wh) + bh — one wave.
__global__ void final_dot(const float* __restrict__ agg,
                          const float* __restrict__ Wh,
                          const float* __restrict__ bh,
                          float* __restrict__ out)
{
    const int t = threadIdx.x;  // 64 threads = 1 wave
    float v = agg[t] * Wh[t];
    #pragma unroll
    for (int o = 32; o > 0; o >>= 1) v += __shfl_down(v, o);
    if (t == 0) out[0] = v + bh[0];
}

extern "C" void kernel_launch(void* const* d_in, const int* in_sizes, int n_in,
                              void* d_out, int out_size, void* d_ws, size_t ws_size,
                              hipStream_t stream) {
    const float* state = (const float*)d_in[0];   // [8192,512]
    const float* W1    = (const float*)d_in[1];   // [512,256]
    const float* b1    = (const float*)d_in[2];   // [256]
    const float* W2    = (const float*)d_in[3];   // [256,256]
    const float* b2    = (const float*)d_in[4];   // [256]
    const float* Wq    = (const float*)d_in[5];   // [256,64]
    const float* bq    = (const float*)d_in[6];   // [64]
    const float* Wh    = (const float*)d_in[7];   // [64]
    const float* bh    = (const float*)d_in[8];   // [1]

    float* enc1 = (float*)d_ws;                               // 8192*256 fp32 (8 MB)
    float* enc2 = enc1 + (size_t)N_ROWS * H_DIM;              // 8192*256 fp32 (8 MB)
    float* agg  = enc2 + (size_t)N_ROWS * H_DIM;              // 64 fp32

    hipMemsetAsync(agg, 0, W_DIM * sizeof(float), stream);

    // enc1 = relu(state @ W1 + b1)   [8192,512]x[512,256]
    gemm_bias_relu<<<dim3(N_ROWS / BM, H_DIM / BN), 256, 0, stream>>>(
        state, W1, b1, enc1, F_IN, H_DIM);
    // enc2 = relu(enc1 @ W2 + b2)    [8192,256]x[256,256]
    gemm_bias_relu<<<dim3(N_ROWS / BM, H_DIM / BN), 256, 0, stream>>>(
        enc1, W2, b2, enc2, H_DIM, H_DIM);
    // agg = colsum(tanh(enc2 @ Wq + bq))
    gemm_tanh_colsum<<<dim3(N_ROWS / BM, 1), 256, 0, stream>>>(
        enc2, Wq, bq, agg);
    // out = agg @ Wh + bh
    final_dot<<<1, 64, 0, stream>>>(agg, Wh, bh, (float*)d_out);
}

// Round 3
// 129.872 us; speedup vs baseline: 1.1233x; 1.1233x over previous
//
#include <hip/hip_runtime.h>
#include <hip/hip_bf16.h>
#include <math.h>

// out = colsum( tanh( relu( relu(S@W1+b1)@W2+b2 )@Wq+bq ) ) @ Wh + bh
// (graph stage is a no-op: all edge weights 1.0 => mean_w == 1.0 everywhere)
//
// Round 3: split-bf16 MFMA. Every fp32 operand v = hi + lo (hi=bf16(v),
// lo=bf16(v-hi)); A@B = Ah@Bh + Al@Bh + Ah@Bl (lo*lo dropped, ~2^-16 rel).
// Intermediates enc1/enc2 stay fp32 in ws; split happens during LDS staging.

#define N_ROWS 8192
#define F_IN   512
#define H_DIM  256
#define W_DIM  64

#define LDA 40   // LDS leading dim pad (bf16): 16B-aligned frags, no 8-way conflicts

using bf16x8 = __attribute__((ext_vector_type(8))) short;
using f32x4  = __attribute__((ext_vector_type(4))) float;
typedef __hip_bfloat16 bf16;

__device__ __forceinline__ void split2(float v, bf16& hi, bf16& lo) {
    bf16 h = __float2bfloat16(v);
    hi = h;
    lo = __float2bfloat16(v - __bfloat162float(h));
}

// ---- weight convert+transpose+split: W[K][N] fp32 -> Wt_hi/lo[N][K] bf16 ----
__global__ __launch_bounds__(256) void convert_weights(
    const float* __restrict__ W1, const float* __restrict__ W2,
    const float* __restrict__ Wq,
    bf16* __restrict__ W1h, bf16* __restrict__ W1l,
    bf16* __restrict__ W2h, bf16* __restrict__ W2l,
    bf16* __restrict__ Wqh, bf16* __restrict__ Wql)
{
    int idx = blockIdx.x * 256 + threadIdx.x;
    if (idx < F_IN * H_DIM) {                 // W1 [512][256] -> [256][512]
        int k = idx >> 8, n = idx & 255;
        split2(W1[idx], W1h[n * F_IN + k], W1l[n * F_IN + k]);
        return;
    }
    idx -= F_IN * H_DIM;
    if (idx < H_DIM * H_DIM) {                // W2 [256][256] -> [256][256]
        int k = idx >> 8, n = idx & 255;
        split2(W2[idx], W2h[n * H_DIM + k], W2l[n * H_DIM + k]);
        return;
    }
    idx -= H_DIM * H_DIM;
    if (idx < H_DIM * W_DIM) {                // Wq [256][64] -> [64][256]
        int k = idx >> 6, n = idx & 63;
        split2(Wq[idx], Wqh[n * H_DIM + k], Wql[n * H_DIM + k]);
    }
}

// ---- C_fp32[8192,256] = relu(A_fp32[8192,K] @ W + bias), split-bf16 MFMA ----
// BM=128, BN=64, BK=32; 4 waves; wave w: rows w*32..+32, 2x4 16x16 frags.
__global__ __launch_bounds__(256) void gemm_relu_split(
    const float* __restrict__ A,
    const bf16* __restrict__ Bh, const bf16* __restrict__ Bl,
    const float* __restrict__ bias, float* __restrict__ C, int K)
{
    __shared__ bf16 Ash[128 * LDA];
    __shared__ bf16 Asl[128 * LDA];
    __shared__ bf16 Bsh[64 * LDA];
    __shared__ bf16 Bsl[64 * LDA];
    const int t = threadIdx.x;
    const int w = t >> 6, l = t & 63, quad = l >> 4, m16 = l & 15;
    const int row0 = blockIdx.x * 128, col0 = blockIdx.y * 64;

    const int arow = t >> 1, ahalf = (t & 1) << 4;   // 16 fp32 per thread
    const int brow = t >> 2, bseg = (t & 3) << 3;    // 8 bf16 per thread

    f32x4 acc[2][4] = {};

    for (int k0 = 0; k0 < K; k0 += 32) {
        const float* ap = A + (size_t)(row0 + arow) * K + k0 + ahalf;
        bf16* adh = &Ash[arow * LDA + ahalf];
        bf16* adl = &Asl[arow * LDA + ahalf];
        #pragma unroll
        for (int i = 0; i < 16; i += 4) {
            float4 v = *(const float4*)(ap + i);
            split2(v.x, adh[i + 0], adl[i + 0]);
            split2(v.y, adh[i + 1], adl[i + 1]);
            split2(v.z, adh[i + 2], adl[i + 2]);
            split2(v.w, adh[i + 3], adl[i + 3]);
        }
        const size_t boff = (size_t)(col0 + brow) * K + k0 + bseg;
        *(bf16x8*)(&Bsh[brow * LDA + bseg]) = *(const bf16x8*)(Bh + boff);
        *(bf16x8*)(&Bsl[brow * LDA + bseg]) = *(const bf16x8*)(Bl + boff);
        __syncthreads();

        const int a0off = (w * 32 + m16) * LDA + quad * 8;
        const int a1off = a0off + 16 * LDA;
        bf16x8 a0h = *(const bf16x8*)(&Ash[a0off]);
        bf16x8 a0l = *(const bf16x8*)(&Asl[a0off]);
        bf16x8 a1h = *(const bf16x8*)(&Ash[a1off]);
        bf16x8 a1l = *(const bf16x8*)(&Asl[a1off]);
        #pragma unroll
        for (int j = 0; j < 4; ++j) {
            const int boff2 = (j * 16 + m16) * LDA + quad * 8;
            bf16x8 bh = *(const bf16x8*)(&Bsh[boff2]);
            bf16x8 bl = *(const bf16x8*)(&Bsl[boff2]);
            acc[0][j] = __builtin_amdgcn_mfma_f32_16x16x32_bf16(a0h, bh, acc[0][j], 0, 0, 0);
            acc[0][j] = __builtin_amdgcn_mfma_f32_16x16x32_bf16(a0l, bh, acc[0][j], 0, 0, 0);
            acc[0][j] = __builtin_amdgcn_mfma_f32_16x16x32_bf16(a0h, bl, acc[0][j], 0, 0, 0);
            acc[1][j] = __builtin_amdgcn_mfma_f32_16x16x32_bf16(a1h, bh, acc[1][j], 0, 0, 0);
            acc[1][j] = __builtin_amdgcn_mfma_f32_16x16x32_bf16(a1l, bh, acc[1][j], 0, 0, 0);
            acc[1][j] = __builtin_amdgcn_mfma_f32_16x16x32_bf16(a1h, bl, acc[1][j], 0, 0, 0);
        }
        __syncthreads();
    }

    #pragma unroll
    for (int i = 0; i < 2; ++i) {
        const int r0 = row0 + w * 32 + i * 16 + quad * 4;
        #pragma unroll
        for (int j = 0; j < 4; ++j) {
            const int c = col0 + j * 16 + m16;
            const float bv = bias[c];
            #pragma unroll
            for (int r = 0; r < 4; ++r)
                C[(size_t)(r0 + r) * H_DIM + c] = fmaxf(acc[i][j][r] + bv, 0.0f);
        }
    }
}

// ---- agg[64] += colsum(tanh(A_fp32[8192,256] @ Wq + bq)), split-bf16 ----
// BM=64, BN=64; wave w: rows w*16..+16, 1x4 frags. Grid (128).
__global__ __launch_bounds__(256) void gemm3_split(
    const float* __restrict__ A,
    const bf16* __restrict__ Bh, const bf16* __restrict__ Bl,
    const float* __restrict__ bias, float* __restrict__ agg)
{
    const int K = H_DIM;
    __shared__ bf16 Ash[64 * LDA];
    __shared__ bf16 Asl[64 * LDA];
    __shared__ bf16 Bsh[64 * LDA];
    __shared__ bf16 Bsl[64 * LDA];
    __shared__ float red[4][64];
    const int t = threadIdx.x;
    const int w = t >> 6, l = t & 63, quad = l >> 4, m16 = l & 15;
    const int row0 = blockIdx.x * 64;

    const int arow = t >> 2, aseg = (t & 3) << 3;   // 8 fp32 per thread
    const int brow = t >> 2, bseg = (t & 3) << 3;   // 8 bf16 per thread

    f32x4 acc[4] = {};

    for (int k0 = 0; k0 < K; k0 += 32) {
        const float* ap = A + (size_t)(row0 + arow) * K + k0 + aseg;
        bf16* adh = &Ash[arow * LDA + aseg];
        bf16* adl = &Asl[arow * LDA + aseg];
        #pragma unroll
        for (int i = 0; i < 8; i += 4) {
            float4 v = *(const float4*)(ap + i);
            split2(v.x, adh[i + 0], adl[i + 0]);
            split2(v.y, adh[i + 1], adl[i + 1]);
            split2(v.z, adh[i + 2], adl[i + 2]);
            split2(v.w, adh[i + 3], adl[i + 3]);
        }
        const size_t boff = (size_t)brow * K + k0 + bseg;
        *(bf16x8*)(&Bsh[brow * LDA + bseg]) = *(const bf16x8*)(Bh + boff);
        *(bf16x8*)(&Bsl[brow * LDA + bseg]) = *(const bf16x8*)(Bl + boff);
        __syncthreads();

        const int a0off = (w * 16 + m16) * LDA + quad * 8;
        bf16x8 a0h = *(const bf16x8*)(&Ash[a0off]);
        bf16x8 a0l = *(const bf16x8*)(&Asl[a0off]);
        #pragma unroll
        for (int j = 0; j < 4; ++j) {
            const int boff2 = (j * 16 + m16) * LDA + quad * 8;
            bf16x8 bh = *(const bf16x8*)(&Bsh[boff2]);
            bf16x8 bl = *(const bf16x8*)(&Bsl[boff2]);
            acc[j] = __builtin_amdgcn_mfma_f32_16x16x32_bf16(a0h, bh, acc[j], 0, 0, 0);
            acc[j] = __builtin_amdgcn_mfma_f32_16x16x32_bf16(a0l, bh, acc[j], 0, 0, 0);
            acc[j] = __builtin_amdgcn_mfma_f32_16x16x32_bf16(a0h, bl, acc[j], 0, 0, 0);
        }
        __syncthreads();
    }

    #pragma unroll
    for (int j = 0; j < 4; ++j) {
        const int c = j * 16 + m16;
        const float bv = bias[c];
        float v = 0.f;
        #pragma unroll
        for (int r = 0; r < 4; ++r)
            v += tanhf(acc[j][r] + bv);
        v += __shfl_xor(v, 16, 64);
        v += __shfl_xor(v, 32, 64);
        if (quad == 0) red[w][c] = v;
    }
    __syncthreads();
    if (t < W_DIM) {
        float s = red[0][t] + red[1][t] + red[2][t] + red[3][t];
        atomicAdd(&agg[t], s);
    }
}

// ---- out[0] = dot(agg, Wh) + bh ----
__global__ void final_dot(const float* __restrict__ agg,
                          const float* __restrict__ Wh,
                          const float* __restrict__ bh,
                          float* __restrict__ out)
{
    const int t = threadIdx.x;
    float v = agg[t] * Wh[t];
    #pragma unroll
    for (int o = 32; o > 0; o >>= 1) v += __shfl_down(v, o);
    if (t == 0) out[0] = v + bh[0];
}

extern "C" void kernel_launch(void* const* d_in, const int* in_sizes, int n_in,
                              void* d_out, int out_size, void* d_ws, size_t ws_size,
                              hipStream_t stream) {
    const float* state = (const float*)d_in[0];
    const float* W1    = (const float*)d_in[1];
    const float* b1    = (const float*)d_in[2];
    const float* W2    = (const float*)d_in[3];
    const float* b2    = (const float*)d_in[4];
    const float* Wq    = (const float*)d_in[5];
    const float* bq    = (const float*)d_in[6];
    const float* Wh    = (const float*)d_in[7];
    const float* bh    = (const float*)d_in[8];

    float* enc1 = (float*)d_ws;                        // 8192*256 fp32 (8 MB)
    float* enc2 = enc1 + (size_t)N_ROWS * H_DIM;       // 8 MB
    bf16* W1h = (bf16*)(enc2 + (size_t)N_ROWS * H_DIM);
    bf16* W1l = W1h + (size_t)H_DIM * F_IN;
    bf16* W2h = W1l + (size_t)H_DIM * F_IN;
    bf16* W2l = W2h + (size_t)H_DIM * H_DIM;
    bf16* Wqh = W2l + (size_t)H_DIM * H_DIM;
    bf16* Wql = Wqh + (size_t)W_DIM * H_DIM;
    float* agg = (float*)(Wql + (size_t)W_DIM * H_DIM);

    hipMemsetAsync(agg, 0, W_DIM * sizeof(float), stream);

    const int conv_elems = F_IN * H_DIM + H_DIM * H_DIM + H_DIM * W_DIM;
    convert_weights<<<(conv_elems + 255) / 256, 256, 0, stream>>>(
        W1, W2, Wq, W1h, W1l, W2h, W2l, Wqh, Wql);

    gemm_relu_split<<<dim3(N_ROWS / 128, H_DIM / 64), 256, 0, stream>>>(
        state, W1h, W1l, b1, enc1, F_IN);
    gemm_relu_split<<<dim3(N_ROWS / 128, H_DIM / 64), 256, 0, stream>>>(
        enc1, W2h, W2l, b2, enc2, H_DIM);
    gemm3_split<<<dim3(N_ROWS / 64), 256, 0, stream>>>(
        enc2, Wqh, Wql, bq, agg);
    final_dot<<<1, 64, 0, stream>>>(agg, Wh, bh, (float*)d_out);
}

// Round 4
// 127.763 us; speedup vs baseline: 1.1419x; 1.0165x over previous
//
#include <hip/hip_runtime.h>
#include <hip/hip_bf16.h>
#include <math.h>

// out = colsum( tanh( relu( relu(S@W1+b1)@W2+b2 )@Wq+bq ) ) @ Wh + bh
// (graph stage is a no-op: all edge weights 1.0 => mean_w == 1.0 everywhere)
//
// Round 4: split-bf16 MFMA with ALL splits hoisted out of the K-loops.
// prep: S -> Sh/Sl planes; W* -> transposed hi/lo planes. GEMM epilogues
// write hi/lo planes directly. K-loops stage pure bf16 via ds_write_b128.

#define N_ROWS 8192
#define F_IN   512
#define H_DIM  256
#define W_DIM  64
#define LDA 40   // LDS leading dim (bf16): 80 B stride -> 2-way max on frag reads

#define W1_E (F_IN * H_DIM)
#define W2_E (H_DIM * H_DIM)
#define WQ_E (H_DIM * W_DIM)
#define S_BLOCKS 2048                     // 8192*512 / (256*8)
#define W_BLOCKS ((W1_E + W2_E + WQ_E + 255) / 256)

using bf16x8 = __attribute__((ext_vector_type(8))) short;
using f32x4  = __attribute__((ext_vector_type(4))) float;
typedef __hip_bfloat16 bf16;

__device__ __forceinline__ void split2(float v, bf16& hi, bf16& lo) {
    bf16 h = __float2bfloat16(v);
    hi = h;
    lo = __float2bfloat16(v - __bfloat162float(h));
}

// ---- prep: split state (vectorized), split+transpose weights, zero agg ----
__global__ __launch_bounds__(256) void prep(
    const float* __restrict__ S, const float* __restrict__ W1,
    const float* __restrict__ W2, const float* __restrict__ Wq,
    bf16* __restrict__ Sh, bf16* __restrict__ Sl,
    bf16* __restrict__ W1h, bf16* __restrict__ W1l,
    bf16* __restrict__ W2h, bf16* __restrict__ W2l,
    bf16* __restrict__ Wqh, bf16* __restrict__ Wql,
    float* __restrict__ agg)
{
    const int b = blockIdx.x, t = threadIdx.x;
    if (b < S_BLOCKS) {
        const size_t base = (size_t)b * 2048 + (size_t)t * 8;
        float4 v0 = *(const float4*)(S + base);
        float4 v1 = *(const float4*)(S + base + 4);
        bf16 hb[8], lb[8];
        split2(v0.x, hb[0], lb[0]); split2(v0.y, hb[1], lb[1]);
        split2(v0.z, hb[2], lb[2]); split2(v0.w, hb[3], lb[3]);
        split2(v1.x, hb[4], lb[4]); split2(v1.y, hb[5], lb[5]);
        split2(v1.z, hb[6], lb[6]); split2(v1.w, hb[7], lb[7]);
        *(bf16x8*)(Sh + base) = *(const bf16x8*)hb;
        *(bf16x8*)(Sl + base) = *(const bf16x8*)lb;
        return;
    }
    if (b == S_BLOCKS && t < W_DIM) agg[t] = 0.0f;
    int gid = (b - S_BLOCKS) * 256 + t;
    if (gid < W1_E) {                       // W1 [512][256] -> [256][512]
        int k = gid >> 8, n = gid & 255;
        split2(W1[gid], W1h[n * F_IN + k], W1l[n * F_IN + k]);
        return;
    }
    gid -= W1_E;
    if (gid < W2_E) {                       // W2 [256][256] -> [256][256]
        int k = gid >> 8, n = gid & 255;
        split2(W2[gid], W2h[n * H_DIM + k], W2l[n * H_DIM + k]);
        return;
    }
    gid -= W2_E;
    if (gid < WQ_E) {                       // Wq [256][64] -> [64][256]
        int k = gid >> 6, n = gid & 63;
        split2(Wq[gid], Wqh[n * H_DIM + k], Wql[n * H_DIM + k]);
    }
}

// ---- C = relu(A @ B^T + bias); A,B,C all hi/lo bf16 planes. ----
// BM=128, BN=64, BK=32; 4 waves; wave w: rows w*32..+32, 2x4 16x16 frags.
__global__ __launch_bounds__(256) void gemm_split(
    const bf16* __restrict__ Ah, const bf16* __restrict__ Al,
    const bf16* __restrict__ Bh, const bf16* __restrict__ Bl,
    const float* __restrict__ bias,
    bf16* __restrict__ Ch, bf16* __restrict__ Cl, int K)
{
    __shared__ bf16 Ash[128 * LDA];
    __shared__ bf16 Asl[128 * LDA];
    __shared__ bf16 Bsh[64 * LDA];
    __shared__ bf16 Bsl[64 * LDA];
    const int t = threadIdx.x;
    const int w = t >> 6, l = t & 63, quad = l >> 4, m16 = l & 15;
    const int row0 = blockIdx.x * 128, col0 = blockIdx.y * 64;

    const int arow = t >> 1, acol = (t & 1) << 4;        // 16 elems hi + 16 lo
    const int brow = t & 63, bcol = ((t >> 6) & 1) << 4; // 16 elems of one part
    const bf16* Bsrc = (t >> 7) ? Bl : Bh;
    bf16*       Bdst = (t >> 7) ? Bsl : Bsh;

    f32x4 acc[2][4] = {};

    for (int k0 = 0; k0 < K; k0 += 32) {
        const size_t aoff = (size_t)(row0 + arow) * K + k0 + acol;
        *(bf16x8*)&Ash[arow * LDA + acol]     = *(const bf16x8*)(Ah + aoff);
        *(bf16x8*)&Ash[arow * LDA + acol + 8] = *(const bf16x8*)(Ah + aoff + 8);
        *(bf16x8*)&Asl[arow * LDA + acol]     = *(const bf16x8*)(Al + aoff);
        *(bf16x8*)&Asl[arow * LDA + acol + 8] = *(const bf16x8*)(Al + aoff + 8);
        const size_t boff = (size_t)(col0 + brow) * K + k0 + bcol;
        *(bf16x8*)&Bdst[brow * LDA + bcol]     = *(const bf16x8*)(Bsrc + boff);
        *(bf16x8*)&Bdst[brow * LDA + bcol + 8] = *(const bf16x8*)(Bsrc + boff + 8);
        __syncthreads();

        const int a0off = (w * 32 + m16) * LDA + quad * 8;
        const int a1off = a0off + 16 * LDA;
        bf16x8 a0h = *(const bf16x8*)(&Ash[a0off]);
        bf16x8 a0l = *(const bf16x8*)(&Asl[a0off]);
        bf16x8 a1h = *(const bf16x8*)(&Ash[a1off]);
        bf16x8 a1l = *(const bf16x8*)(&Asl[a1off]);
        #pragma unroll
        for (int j = 0; j < 4; ++j) {
            const int bo = (j * 16 + m16) * LDA + quad * 8;
            bf16x8 bh = *(const bf16x8*)(&Bsh[bo]);
            bf16x8 bl = *(const bf16x8*)(&Bsl[bo]);
            acc[0][j] = __builtin_amdgcn_mfma_f32_16x16x32_bf16(a0h, bh, acc[0][j], 0, 0, 0);
            acc[0][j] = __builtin_amdgcn_mfma_f32_16x16x32_bf16(a0l, bh, acc[0][j], 0, 0, 0);
            acc[0][j] = __builtin_amdgcn_mfma_f32_16x16x32_bf16(a0h, bl, acc[0][j], 0, 0, 0);
            acc[1][j] = __builtin_amdgcn_mfma_f32_16x16x32_bf16(a1h, bh, acc[1][j], 0, 0, 0);
            acc[1][j] = __builtin_amdgcn_mfma_f32_16x16x32_bf16(a1l, bh, acc[1][j], 0, 0, 0);
            acc[1][j] = __builtin_amdgcn_mfma_f32_16x16x32_bf16(a1h, bl, acc[1][j], 0, 0, 0);
        }
        __syncthreads();
    }

    #pragma unroll
    for (int i = 0; i < 2; ++i) {
        const int r0 = row0 + w * 32 + i * 16 + quad * 4;
        #pragma unroll
        for (int j = 0; j < 4; ++j) {
            const int c = col0 + j * 16 + m16;
            const float bv = bias[c];
            #pragma unroll
            for (int r = 0; r < 4; ++r) {
                float v = fmaxf(acc[i][j][r] + bv, 0.0f);
                const size_t o = (size_t)(r0 + r) * H_DIM + c;
                split2(v, Ch[o], Cl[o]);
            }
        }
    }
}

// ---- agg[64] += colsum(tanh(A @ Wq^T + bq)); A hi/lo bf16 planes ----
// BM=64, BN=64; wave w: rows w*16..+16, 1x4 frags. Grid (128).
__global__ __launch_bounds__(256) void gemm3_split(
    const bf16* __restrict__ Ah, const bf16* __restrict__ Al,
    const bf16* __restrict__ Bh, const bf16* __restrict__ Bl,
    const float* __restrict__ bias, float* __restrict__ agg)
{
    const int K = H_DIM;
    __shared__ bf16 Ash[64 * LDA];
    __shared__ bf16 Asl[64 * LDA];
    __shared__ bf16 Bsh[64 * LDA];
    __shared__ bf16 Bsl[64 * LDA];
    __shared__ float red[4][64];
    const int t = threadIdx.x;
    const int w = t >> 6, l = t & 63, quad = l >> 4, m16 = l & 15;
    const int row0 = blockIdx.x * 64;

    const int arow = (t & 127) >> 1, acol = (t & 1) << 4;
    const bf16* Asrc = (t >> 7) ? Al : Ah;
    bf16*       Adst = (t >> 7) ? Asl : Ash;
    const int brow = t & 63, bcol = ((t >> 6) & 1) << 4;
    const bf16* Bsrc = (t >> 7) ? Bl : Bh;
    bf16*       Bdst = (t >> 7) ? Bsl : Bsh;

    f32x4 acc[4] = {};

    for (int k0 = 0; k0 < K; k0 += 32) {
        const size_t aoff = (size_t)(row0 + arow) * K + k0 + acol;
        *(bf16x8*)&Adst[arow * LDA + acol]     = *(const bf16x8*)(Asrc + aoff);
        *(bf16x8*)&Adst[arow * LDA + acol + 8] = *(const bf16x8*)(Asrc + aoff + 8);
        const size_t boff = (size_t)brow * K + k0 + bcol;
        *(bf16x8*)&Bdst[brow * LDA + bcol]     = *(const bf16x8*)(Bsrc + boff);
        *(bf16x8*)&Bdst[brow * LDA + bcol + 8] = *(const bf16x8*)(Bsrc + boff + 8);
        __syncthreads();

        const int a0off = (w * 16 + m16) * LDA + quad * 8;
        bf16x8 a0h = *(const bf16x8*)(&Ash[a0off]);
        bf16x8 a0l = *(const bf16x8*)(&Asl[a0off]);
        #pragma unroll
        for (int j = 0; j < 4; ++j) {
            const int bo = (j * 16 + m16) * LDA + quad * 8;
            bf16x8 bh = *(const bf16x8*)(&Bsh[bo]);
            bf16x8 bl = *(const bf16x8*)(&Bsl[bo]);
            acc[j] = __builtin_amdgcn_mfma_f32_16x16x32_bf16(a0h, bh, acc[j], 0, 0, 0);
            acc[j] = __builtin_amdgcn_mfma_f32_16x16x32_bf16(a0l, bh, acc[j], 0, 0, 0);
            acc[j] = __builtin_amdgcn_mfma_f32_16x16x32_bf16(a0h, bl, acc[j], 0, 0, 0);
        }
        __syncthreads();
    }

    #pragma unroll
    for (int j = 0; j < 4; ++j) {
        const int c = j * 16 + m16;
        const float bv = bias[c];
        float v = 0.f;
        #pragma unroll
        for (int r = 0; r < 4; ++r)
            v += tanhf(acc[j][r] + bv);
        v += __shfl_xor(v, 16, 64);
        v += __shfl_xor(v, 32, 64);
        if (quad == 0) red[w][c] = v;
    }
    __syncthreads();
    if (t < W_DIM) {
        float s = red[0][t] + red[1][t] + red[2][t] + red[3][t];
        atomicAdd(&agg[t], s);
    }
}

// ---- out[0] = dot(agg, Wh) + bh ----
__global__ void final_dot(const float* __restrict__ agg,
                          const float* __restrict__ Wh,
                          const float* __restrict__ bh,
                          float* __restrict__ out)
{
    const int t = threadIdx.x;
    float v = agg[t] * Wh[t];
    #pragma unroll
    for (int o = 32; o > 0; o >>= 1) v += __shfl_down(v, o);
    if (t == 0) out[0] = v + bh[0];
}

extern "C" void kernel_launch(void* const* d_in, const int* in_sizes, int n_in,
                              void* d_out, int out_size, void* d_ws, size_t ws_size,
                              hipStream_t stream) {
    const float* state = (const float*)d_in[0];
    const float* W1    = (const float*)d_in[1];
    const float* b1    = (const float*)d_in[2];
    const float* W2    = (const float*)d_in[3];
    const float* b2    = (const float*)d_in[4];
    const float* Wq    = (const float*)d_in[5];
    const float* bq    = (const float*)d_in[6];
    const float* Wh    = (const float*)d_in[7];
    const float* bh    = (const float*)d_in[8];

    bf16* p = (bf16*)d_ws;
    bf16* Sh  = p; p += (size_t)N_ROWS * F_IN;    // 8 MB
    bf16* Sl  = p; p += (size_t)N_ROWS * F_IN;    // 8 MB
    bf16* E1h = p; p += (size_t)N_ROWS * H_DIM;   // 4 MB
    bf16* E1l = p; p += (size_t)N_ROWS * H_DIM;
    bf16* E2h = p; p += (size_t)N_ROWS * H_DIM;
    bf16* E2l = p; p += (size_t)N_ROWS * H_DIM;
    bf16* W1h = p; p += (size_t)H_DIM * F_IN;
    bf16* W1l = p; p += (size_t)H_DIM * F_IN;
    bf16* W2h = p; p += (size_t)H_DIM * H_DIM;
    bf16* W2l = p; p += (size_t)H_DIM * H_DIM;
    bf16* Wqh = p; p += (size_t)W_DIM * H_DIM;
    bf16* Wql = p; p += (size_t)W_DIM * H_DIM;
    float* agg = (float*)p;

    prep<<<S_BLOCKS + W_BLOCKS, 256, 0, stream>>>(
        state, W1, W2, Wq, Sh, Sl, W1h, W1l, W2h, W2l, Wqh, Wql, agg);

    gemm_split<<<dim3(N_ROWS / 128, H_DIM / 64), 256, 0, stream>>>(
        Sh, Sl, W1h, W1l, b1, E1h, E1l, F_IN);
    gemm_split<<<dim3(N_ROWS / 128, H_DIM / 64), 256, 0, stream>>>(
        E1h, E1l, W2h, W2l, b2, E2h, E2l, H_DIM);
    gemm3_split<<<dim3(N_ROWS / 64), 256, 0, stream>>>(
        E2h, E2l, Wqh, Wql, bq, agg);
    final_dot<<<1, 64, 0, stream>>>(agg, Wh, bh, (float*)d_out);
}

// Round 5
// 127.371 us; speedup vs baseline: 1.1454x; 1.0031x over previous
//
#include <hip/hip_runtime.h>
#include <hip/hip_bf16.h>
#include <math.h>

// out = colsum( tanh( relu( relu(S@W1+b1)@W2+b2 )@Wq+bq ) ) @ Wh + bh
// (graph stage is a no-op: all edge weights 1.0 => mean_w == 1.0 everywhere)
//
// Round 5: split-bf16 MFMA (v = hi+lo; A@B = AhBh + AlBh + AhBl, fp32-class).
// - gemm1 splits fp32 state in registers (packed bf16x8 -> ds_write_b128)
// - BM=BN=64 tiles -> 512 blocks = 2/CU for barrier-drain overlap
// - gemm3 folds colsum, dot(Wh) and +bh, atomicAdd straight to out[0]

#define N_ROWS 8192
#define F_IN   512
#define H_DIM  256
#define W_DIM  64
#define LDA 40   // LDS leading dim (bf16): 80 B stride, 16B-aligned frags

#define W1_E (F_IN * H_DIM)
#define W2_E (H_DIM * H_DIM)
#define WQ_E (H_DIM * W_DIM)
#define W_BLOCKS ((W1_E + W2_E + WQ_E + 255) / 256)

using bf16x8 = __attribute__((ext_vector_type(8))) short;
using f32x4  = __attribute__((ext_vector_type(4))) float;
typedef __hip_bfloat16 bf16;

__device__ __forceinline__ void split2(float v, bf16& hi, bf16& lo) {
    bf16 h = __float2bfloat16(v);
    hi = h;
    lo = __float2bfloat16(v - __bfloat162float(h));
}

// ---- weight split+transpose: W[K][N] fp32 -> hi/lo [N][K] bf16 ----
__global__ __launch_bounds__(256) void prep_w(
    const float* __restrict__ W1, const float* __restrict__ W2,
    const float* __restrict__ Wq,
    bf16* __restrict__ W1h, bf16* __restrict__ W1l,
    bf16* __restrict__ W2h, bf16* __restrict__ W2l,
    bf16* __restrict__ Wqh, bf16* __restrict__ Wql)
{
    int gid = blockIdx.x * 256 + threadIdx.x;
    if (gid < W1_E) {                       // W1 [512][256] -> [256][512]
        int k = gid >> 8, n = gid & 255;
        split2(W1[gid], W1h[n * F_IN + k], W1l[n * F_IN + k]);
        return;
    }
    gid -= W1_E;
    if (gid < W2_E) {                       // W2 [256][256] -> [256][256]
        int k = gid >> 8, n = gid & 255;
        split2(W2[gid], W2h[n * H_DIM + k], W2l[n * H_DIM + k]);
        return;
    }
    gid -= W2_E;
    if (gid < WQ_E) {                       // Wq [256][64] -> [64][256]
        int k = gid >> 6, n = gid & 63;
        split2(Wq[gid], Wqh[n * H_DIM + k], Wql[n * H_DIM + k]);
    }
}

// ---- GEMM1: E1 = relu(S_fp32 @ W1^T + b1); split S in registers ----
// BM=BN=64, BK=32, 4 waves; wave w: rows w*16..+16 (1 m-frag x 4 n-frags).
__global__ __launch_bounds__(256) void gemm1_fused(
    const float* __restrict__ A,
    const bf16* __restrict__ Bh, const bf16* __restrict__ Bl,
    const float* __restrict__ bias,
    bf16* __restrict__ Ch, bf16* __restrict__ Cl)
{
    const int K = F_IN;
    __shared__ bf16 Ash[64 * LDA];
    __shared__ bf16 Asl[64 * LDA];
    __shared__ bf16 Bsh[64 * LDA];
    __shared__ bf16 Bsl[64 * LDA];
    const int t = threadIdx.x;
    const int w = t >> 6, quad = (t & 63) >> 4, m16 = t & 15;
    const int row0 = blockIdx.x * 64, col0 = blockIdx.y * 64;

    const int arow = t >> 2, acol = (t & 3) << 3;        // 8 fp32 each
    const int brow = t & 63, bk = ((t >> 6) & 1) << 4;   // 16 bf16 of one plane
    const bf16* Bsrc = (t >> 7) ? Bl : Bh;
    bf16*       Bdst = (t >> 7) ? Bsl : Bsh;

    f32x4 acc[4] = {};

    for (int k0 = 0; k0 < K; k0 += 32) {
        float4 v0 = *(const float4*)(A + (size_t)(row0 + arow) * K + k0 + acol);
        float4 v1 = *(const float4*)(A + (size_t)(row0 + arow) * K + k0 + acol + 4);
        bf16 hb[8], lb[8];
        split2(v0.x, hb[0], lb[0]); split2(v0.y, hb[1], lb[1]);
        split2(v0.z, hb[2], lb[2]); split2(v0.w, hb[3], lb[3]);
        split2(v1.x, hb[4], lb[4]); split2(v1.y, hb[5], lb[5]);
        split2(v1.z, hb[6], lb[6]); split2(v1.w, hb[7], lb[7]);
        *(bf16x8*)&Ash[arow * LDA + acol] = *(const bf16x8*)hb;
        *(bf16x8*)&Asl[arow * LDA + acol] = *(const bf16x8*)lb;
        const size_t boff = (size_t)(col0 + brow) * K + k0 + bk;
        *(bf16x8*)&Bdst[brow * LDA + bk]     = *(const bf16x8*)(Bsrc + boff);
        *(bf16x8*)&Bdst[brow * LDA + bk + 8] = *(const bf16x8*)(Bsrc + boff + 8);
        __syncthreads();

        const int ao = (w * 16 + m16) * LDA + quad * 8;
        bf16x8 a_h = *(const bf16x8*)(&Ash[ao]);
        bf16x8 a_l = *(const bf16x8*)(&Asl[ao]);
        #pragma unroll
        for (int j = 0; j < 4; ++j) {
            const int bo = (j * 16 + m16) * LDA + quad * 8;
            bf16x8 b_h = *(const bf16x8*)(&Bsh[bo]);
            bf16x8 b_l = *(const bf16x8*)(&Bsl[bo]);
            acc[j] = __builtin_amdgcn_mfma_f32_16x16x32_bf16(a_h, b_h, acc[j], 0, 0, 0);
            acc[j] = __builtin_amdgcn_mfma_f32_16x16x32_bf16(a_l, b_h, acc[j], 0, 0, 0);
            acc[j] = __builtin_amdgcn_mfma_f32_16x16x32_bf16(a_h, b_l, acc[j], 0, 0, 0);
        }
        __syncthreads();
    }

    const int r0 = row0 + w * 16 + quad * 4;
    #pragma unroll
    for (int j = 0; j < 4; ++j) {
        const int c = col0 + j * 16 + m16;
        const float bv = bias[c];
        #pragma unroll
        for (int r = 0; r < 4; ++r) {
            float v = fmaxf(acc[j][r] + bv, 0.0f);
            const size_t o = (size_t)(r0 + r) * H_DIM + c;
            split2(v, Ch[o], Cl[o]);
        }
    }
}

// ---- GEMM2: E2 = relu(E1 @ W2^T + b2); all operands hi/lo planes ----
__global__ __launch_bounds__(256) void gemm2_split(
    const bf16* __restrict__ Ah, const bf16* __restrict__ Al,
    const bf16* __restrict__ Bh, const bf16* __restrict__ Bl,
    const float* __restrict__ bias,
    bf16* __restrict__ Ch, bf16* __restrict__ Cl)
{
    const int K = H_DIM;
    __shared__ bf16 Ash[64 * LDA];
    __shared__ bf16 Asl[64 * LDA];
    __shared__ bf16 Bsh[64 * LDA];
    __shared__ bf16 Bsl[64 * LDA];
    const int t = threadIdx.x;
    const int w = t >> 6, quad = (t & 63) >> 4, m16 = t & 15;
    const int row0 = blockIdx.x * 64, col0 = blockIdx.y * 64;

    const int arow = t & 63, ak = ((t >> 6) & 1) << 4;
    const bf16* Asrc = (t >> 7) ? Al : Ah;
    bf16*       Adst = (t >> 7) ? Asl : Ash;
    const bf16* Bsrc = (t >> 7) ? Bl : Bh;
    bf16*       Bdst = (t >> 7) ? Bsl : Bsh;

    f32x4 acc[4] = {};

    for (int k0 = 0; k0 < K; k0 += 32) {
        const size_t aoff = (size_t)(row0 + arow) * K + k0 + ak;
        *(bf16x8*)&Adst[arow * LDA + ak]     = *(const bf16x8*)(Asrc + aoff);
        *(bf16x8*)&Adst[arow * LDA + ak + 8] = *(const bf16x8*)(Asrc + aoff + 8);
        const size_t boff = (size_t)(col0 + arow) * K + k0 + ak;
        *(bf16x8*)&Bdst[arow * LDA + ak]     = *(const bf16x8*)(Bsrc + boff);
        *(bf16x8*)&Bdst[arow * LDA + ak + 8] = *(const bf16x8*)(Bsrc + boff + 8);
        __syncthreads();

        const int ao = (w * 16 + m16) * LDA + quad * 8;
        bf16x8 a_h = *(const bf16x8*)(&Ash[ao]);
        bf16x8 a_l = *(const bf16x8*)(&Asl[ao]);
        #pragma unroll
        for (int j = 0; j < 4; ++j) {
            const int bo = (j * 16 + m16) * LDA + quad * 8;
            bf16x8 b_h = *(const bf16x8*)(&Bsh[bo]);
            bf16x8 b_l = *(const bf16x8*)(&Bsl[bo]);
            acc[j] = __builtin_amdgcn_mfma_f32_16x16x32_bf16(a_h, b_h, acc[j], 0, 0, 0);
            acc[j] = __builtin_amdgcn_mfma_f32_16x16x32_bf16(a_l, b_h, acc[j], 0, 0, 0);
            acc[j] = __builtin_amdgcn_mfma_f32_16x16x32_bf16(a_h, b_l, acc[j], 0, 0, 0);
        }
        __syncthreads();
    }

    const int r0 = row0 + w * 16 + quad * 4;
    #pragma unroll
    for (int j = 0; j < 4; ++j) {
        const int c = col0 + j * 16 + m16;
        const float bv = bias[c];
        #pragma unroll
        for (int r = 0; r < 4; ++r) {
            float v = fmaxf(acc[j][r] + bv, 0.0f);
            const size_t o = (size_t)(r0 + r) * H_DIM + c;
            split2(v, Ch[o], Cl[o]);
        }
    }
}

// ---- GEMM3: out[0] += dot(colsum(tanh(E2 @ Wq^T + bq)), Wh)  (+bh once) ----
// BM=64, BN=64(full). Grid (128).
__global__ __launch_bounds__(256) void gemm3_fused(
    const bf16* __restrict__ Ah, const bf16* __restrict__ Al,
    const bf16* __restrict__ Bh, const bf16* __restrict__ Bl,
    const float* __restrict__ bias, const float* __restrict__ Wh,
    const float* __restrict__ bh, float* __restrict__ out)
{
    const int K = H_DIM;
    __shared__ bf16 Ash[64 * LDA];
    __shared__ bf16 Asl[64 * LDA];
    __shared__ bf16 Bsh[64 * LDA];
    __shared__ bf16 Bsl[64 * LDA];
    __shared__ float red[4][64];
    const int t = threadIdx.x;
    const int w = t >> 6, quad = (t & 63) >> 4, m16 = t & 15;
    const int row0 = blockIdx.x * 64;

    const int arow = t & 63, ak = ((t >> 6) & 1) << 4;
    const bf16* Asrc = (t >> 7) ? Al : Ah;
    bf16*       Adst = (t >> 7) ? Asl : Ash;
    const bf16* Bsrc = (t >> 7) ? Bl : Bh;
    bf16*       Bdst = (t >> 7) ? Bsl : Bsh;

    f32x4 acc[4] = {};

    for (int k0 = 0; k0 < K; k0 += 32) {
        const size_t aoff = (size_t)(row0 + arow) * K + k0 + ak;
        *(bf16x8*)&Adst[arow * LDA + ak]     = *(const bf16x8*)(Asrc + aoff);
        *(bf16x8*)&Adst[arow * LDA + ak + 8] = *(const bf16x8*)(Asrc + aoff + 8);
        const size_t boff = (size_t)arow * K + k0 + ak;
        *(bf16x8*)&Bdst[arow * LDA + ak]     = *(const bf16x8*)(Bsrc + boff);
        *(bf16x8*)&Bdst[arow * LDA + ak + 8] = *(const bf16x8*)(Bsrc + boff + 8);
        __syncthreads();

        const int ao = (w * 16 + m16) * LDA + quad * 8;
        bf16x8 a_h = *(const bf16x8*)(&Ash[ao]);
        bf16x8 a_l = *(const bf16x8*)(&Asl[ao]);
        #pragma unroll
        for (int j = 0; j < 4; ++j) {
            const int bo = (j * 16 + m16) * LDA + quad * 8;
            bf16x8 b_h = *(const bf16x8*)(&Bsh[bo]);
            bf16x8 b_l = *(const bf16x8*)(&Bsl[bo]);
            acc[j] = __builtin_amdgcn_mfma_f32_16x16x32_bf16(a_h, b_h, acc[j], 0, 0, 0);
            acc[j] = __builtin_amdgcn_mfma_f32_16x16x32_bf16(a_l, b_h, acc[j], 0, 0, 0);
            acc[j] = __builtin_amdgcn_mfma_f32_16x16x32_bf16(a_h, b_l, acc[j], 0, 0, 0);
        }
        __syncthreads();
    }

    #pragma unroll
    for (int j = 0; j < 4; ++j) {
        const int c = j * 16 + m16;
        const float bv = bias[c];
        float v = 0.f;
        #pragma unroll
        for (int r = 0; r < 4; ++r)
            v += tanhf(acc[j][r] + bv);
        v += __shfl_xor(v, 16, 64);
        v += __shfl_xor(v, 32, 64);
        if (quad == 0) red[w][c] = v;
    }
    __syncthreads();
    if (t < W_DIM) {               // one wave
        float s = (red[0][t] + red[1][t] + red[2][t] + red[3][t]) * Wh[t];
        #pragma unroll
        for (int o = 32; o > 0; o >>= 1) s += __shfl_down(s, o);
        if (t == 0) {
            if (blockIdx.x == 0) s += bh[0];
            atomicAdd(out, s);
        }
    }
}

extern "C" void kernel_launch(void* const* d_in, const int* in_sizes, int n_in,
                              void* d_out, int out_size, void* d_ws, size_t ws_size,
                              hipStream_t stream) {
    const float* state = (const float*)d_in[0];
    const float* W1    = (const float*)d_in[1];
    const float* b1    = (const float*)d_in[2];
    const float* W2    = (const float*)d_in[3];
    const float* b2    = (const float*)d_in[4];
    const float* Wq    = (const float*)d_in[5];
    const float* bq    = (const float*)d_in[6];
    const float* Wh    = (const float*)d_in[7];
    const float* bh    = (const float*)d_in[8];

    bf16* p = (bf16*)d_ws;
    bf16* E1h = p; p += (size_t)N_ROWS * H_DIM;   // 4 MB
    bf16* E1l = p; p += (size_t)N_ROWS * H_DIM;
    bf16* E2h = p; p += (size_t)N_ROWS * H_DIM;
    bf16* E2l = p; p += (size_t)N_ROWS * H_DIM;
    bf16* W1h = p; p += (size_t)H_DIM * F_IN;
    bf16* W1l = p; p += (size_t)H_DIM * F_IN;
    bf16* W2h = p; p += (size_t)H_DIM * H_DIM;
    bf16* W2l = p; p += (size_t)H_DIM * H_DIM;
    bf16* Wqh = p; p += (size_t)W_DIM * H_DIM;
    bf16* Wql = p; p += (size_t)W_DIM * H_DIM;

    hipMemsetAsync(d_out, 0, sizeof(float), stream);

    prep_w<<<W_BLOCKS, 256, 0, stream>>>(
        W1, W2, Wq, W1h, W1l, W2h, W2l, Wqh, Wql);

    gemm1_fused<<<dim3(N_ROWS / 64, H_DIM / 64), 256, 0, stream>>>(
        state, W1h, W1l, b1, E1h, E1l);
    gemm2_split<<<dim3(N_ROWS / 64, H_DIM / 64), 256, 0, stream>>>(
        E1h, E1l, W2h, W2l, b2, E2h, E2l);
    gemm3_fused<<<dim3(N_ROWS / 64), 256, 0, stream>>>(
        E2h, E2l, Wqh, Wql, bq, Wh, bh, (float*)d_out);
}

// Round 6
// 106.383 us; speedup vs baseline: 1.3713x; 1.1973x over previous
//
#include <hip/hip_runtime.h>
#include <hip/hip_bf16.h>
#include <math.h>

// out = colsum( tanh( relu( relu(S@W1+b1)@W2+b2 )@Wq+bq ) ) @ Wh + bh
// (graph stage is a no-op: all edge weights 1.0 => mean_w == 1.0 everywhere)
//
// Round 6: FULL FUSION. The chain is row-local, so one block owns a 32-row
// strip and flows S -> E1 -> E2 -> tanh -> colsum entirely in LDS. Split-bf16
// MFMA throughout (v = hi+lo; A@B = AhBh + AlBh + AhBl => fp32-class).
// 2 launches total: prep_w (weight split+transpose, seeds out=bh) + fused.
// Weight k-tiles are register-prefetched so global latency hides under MFMA.

#define N_ROWS 8192
#define F_IN   512
#define H_DIM  256
#define W_DIM  64

#define LDW 40    // staging LDS leading dim (bf16): 80 B stride -> 2-way, free
#define LDE 280   // E-plane leading dim: 560 B stride -> 2-way on frag reads

#define W1_E (F_IN * H_DIM)
#define W2_E (H_DIM * H_DIM)
#define WQ_E (H_DIM * W_DIM)
#define W_BLOCKS ((W1_E + W2_E + WQ_E + 255) / 256)

using bf16x8 = __attribute__((ext_vector_type(8))) short;
using f32x4  = __attribute__((ext_vector_type(4))) float;
typedef __hip_bfloat16 bf16;

__device__ __forceinline__ void split2(float v, bf16& hi, bf16& lo) {
    bf16 h = __float2bfloat16(v);
    hi = h;
    lo = __float2bfloat16(v - __bfloat162float(h));
}

// ---- weight split+transpose: W[K][N] fp32 -> hi/lo [N][K] bf16; out = bh ----
__global__ __launch_bounds__(256) void prep_w(
    const float* __restrict__ W1, const float* __restrict__ W2,
    const float* __restrict__ Wq, const float* __restrict__ bh,
    bf16* __restrict__ W1h, bf16* __restrict__ W1l,
    bf16* __restrict__ W2h, bf16* __restrict__ W2l,
    bf16* __restrict__ Wqh, bf16* __restrict__ Wql,
    float* __restrict__ out)
{
    if (blockIdx.x == 0 && threadIdx.x == 0) out[0] = bh[0];
    int gid = blockIdx.x * 256 + threadIdx.x;
    if (gid < W1_E) {                       // W1 [512][256] -> [256][512]
        int k = gid >> 8, n = gid & 255;
        split2(W1[gid], W1h[n * F_IN + k], W1l[n * F_IN + k]);
        return;
    }
    gid -= W1_E;
    if (gid < W2_E) {                       // W2 [256][256] -> [256][256]
        int k = gid >> 8, n = gid & 255;
        split2(W2[gid], W2h[n * H_DIM + k], W2l[n * H_DIM + k]);
        return;
    }
    gid -= W2_E;
    if (gid < WQ_E) {                       // Wq [256][64] -> [64][256]
        int k = gid >> 6, n = gid & 63;
        split2(Wq[gid], Wqh[n * H_DIM + k], Wql[n * H_DIM + k]);
    }
}

// ---- fused: 32-row strip, whole chain in one block ----
// 512 threads = 8 waves. gemm1/2: wave w -> cols 32w..32w+32 (2 col-frags)
// x 2 row-frags. gemm3: wave w -> row-frag w>>2, col-frag w&3.
__global__ __launch_bounds__(512) void fused_chain(
    const float* __restrict__ S,
    const bf16* __restrict__ W1h, const bf16* __restrict__ W1l,
    const bf16* __restrict__ W2h, const bf16* __restrict__ W2l,
    const bf16* __restrict__ Wqh, const bf16* __restrict__ Wql,
    const float* __restrict__ b1, const float* __restrict__ b2,
    const float* __restrict__ bq, const float* __restrict__ Wh,
    float* __restrict__ out)
{
    __shared__ bf16 Ssh[32 * LDW];
    __shared__ bf16 Ssl[32 * LDW];
    __shared__ bf16 Bsh[256 * LDW];
    __shared__ bf16 Bsl[256 * LDW];
    __shared__ bf16 E1h[32 * LDE];
    __shared__ bf16 E1l[32 * LDE];
    __shared__ bf16 E2h[32 * LDE];
    __shared__ bf16 E2l[32 * LDE];
    __shared__ float red[2][64];

    const int t = threadIdx.x;
    const int w = t >> 6, quad = (t & 63) >> 4, m16 = t & 15;
    const int row0 = blockIdx.x * 32;

    // ================= GEMM1: E1 = relu(S @ W1^T + b1) =================
    f32x4 acc[2][2] = {};
    {
        const int srow = t >> 2, ssg = (t & 3) << 3;   // t<128: 8 fp32 of S
        float4 s0 = {0, 0, 0, 0}, s1 = {0, 0, 0, 0};
        bf16x8 wv[4];
        if (t < 128) {
            const float* ap = S + (size_t)(row0 + srow) * F_IN + ssg;
            s0 = *(const float4*)ap;
            s1 = *(const float4*)(ap + 4);
        }
        #pragma unroll
        for (int i = 0; i < 4; ++i) {
            const int v = t + 512 * i, pl = v >> 10, vp = v & 1023;
            const int n = vp >> 2, sg = (vp & 3) << 3;
            wv[i] = *(const bf16x8*)((pl ? W1l : W1h) + (size_t)n * F_IN + sg);
        }
        for (int k0 = 0; k0 < F_IN; k0 += 32) {
            __syncthreads();
            if (t < 128) {
                bf16 hb[8], lb[8];
                split2(s0.x, hb[0], lb[0]); split2(s0.y, hb[1], lb[1]);
                split2(s0.z, hb[2], lb[2]); split2(s0.w, hb[3], lb[3]);
                split2(s1.x, hb[4], lb[4]); split2(s1.y, hb[5], lb[5]);
                split2(s1.z, hb[6], lb[6]); split2(s1.w, hb[7], lb[7]);
                *(bf16x8*)&Ssh[srow * LDW + ssg] = *(const bf16x8*)hb;
                *(bf16x8*)&Ssl[srow * LDW + ssg] = *(const bf16x8*)lb;
            }
            #pragma unroll
            for (int i = 0; i < 4; ++i) {
                const int v = t + 512 * i, pl = v >> 10, vp = v & 1023;
                const int n = vp >> 2, sg = (vp & 3) << 3;
                *(bf16x8*)&(pl ? Bsl : Bsh)[n * LDW + sg] = wv[i];
            }
            __syncthreads();
            if (k0 + 32 < F_IN) {           // prefetch next k-tile
                if (t < 128) {
                    const float* ap = S + (size_t)(row0 + srow) * F_IN + k0 + 32 + ssg;
                    s0 = *(const float4*)ap;
                    s1 = *(const float4*)(ap + 4);
                }
                #pragma unroll
                for (int i = 0; i < 4; ++i) {
                    const int v = t + 512 * i, pl = v >> 10, vp = v & 1023;
                    const int n = vp >> 2, sg = (vp & 3) << 3;
                    wv[i] = *(const bf16x8*)((pl ? W1l : W1h) + (size_t)n * F_IN + k0 + 32 + sg);
                }
            }
            bf16x8 a0h = *(const bf16x8*)(&Ssh[m16 * LDW + quad * 8]);
            bf16x8 a0l = *(const bf16x8*)(&Ssl[m16 * LDW + quad * 8]);
            bf16x8 a1h = *(const bf16x8*)(&Ssh[(16 + m16) * LDW + quad * 8]);
            bf16x8 a1l = *(const bf16x8*)(&Ssl[(16 + m16) * LDW + quad * 8]);
            #pragma unroll
            for (int jj = 0; jj < 2; ++jj) {
                const int bn = (32 * w + jj * 16 + m16) * LDW + quad * 8;
                bf16x8 b_h = *(const bf16x8*)(&Bsh[bn]);
                bf16x8 b_l = *(const bf16x8*)(&Bsl[bn]);
                acc[0][jj] = __builtin_amdgcn_mfma_f32_16x16x32_bf16(a0h, b_h, acc[0][jj], 0, 0, 0);
                acc[0][jj] = __builtin_amdgcn_mfma_f32_16x16x32_bf16(a0l, b_h, acc[0][jj], 0, 0, 0);
                acc[0][jj] = __builtin_amdgcn_mfma_f32_16x16x32_bf16(a0h, b_l, acc[0][jj], 0, 0, 0);
                acc[1][jj] = __builtin_amdgcn_mfma_f32_16x16x32_bf16(a1h, b_h, acc[1][jj], 0, 0, 0);
                acc[1][jj] = __builtin_amdgcn_mfma_f32_16x16x32_bf16(a1l, b_h, acc[1][jj], 0, 0, 0);
                acc[1][jj] = __builtin_amdgcn_mfma_f32_16x16x32_bf16(a1h, b_l, acc[1][jj], 0, 0, 0);
            }
        }
        // epilogue: relu + bias -> E1 hi/lo (LDS)
        #pragma unroll
        for (int i = 0; i < 2; ++i)
            #pragma unroll
            for (int jj = 0; jj < 2; ++jj) {
                const int c = 32 * w + jj * 16 + m16;
                const float bv = b1[c];
                #pragma unroll
                for (int r = 0; r < 4; ++r) {
                    const int rr = i * 16 + quad * 4 + r;
                    float vv = fmaxf(acc[i][jj][r] + bv, 0.0f);
                    split2(vv, E1h[rr * LDE + c], E1l[rr * LDE + c]);
                }
            }
    }

    // ================= GEMM2: E2 = relu(E1 @ W2^T + b2) =================
    {
        bf16x8 wv[4];
        #pragma unroll
        for (int i = 0; i < 4; ++i) {
            const int v = t + 512 * i, pl = v >> 10, vp = v & 1023;
            const int n = vp >> 2, sg = (vp & 3) << 3;
            wv[i] = *(const bf16x8*)((pl ? W2l : W2h) + (size_t)n * H_DIM + sg);
        }
        #pragma unroll
        for (int i = 0; i < 2; ++i)
            #pragma unroll
            for (int jj = 0; jj < 2; ++jj)
                acc[i][jj] = (f32x4){0.f, 0.f, 0.f, 0.f};
        for (int k0 = 0; k0 < H_DIM; k0 += 32) {
            __syncthreads();     // also orders E1 writes before E1 reads
            #pragma unroll
            for (int i = 0; i < 4; ++i) {
                const int v = t + 512 * i, pl = v >> 10, vp = v & 1023;
                const int n = vp >> 2, sg = (vp & 3) << 3;
                *(bf16x8*)&(pl ? Bsl : Bsh)[n * LDW + sg] = wv[i];
            }
            __syncthreads();
            if (k0 + 32 < H_DIM) {
                #pragma unroll
                for (int i = 0; i < 4; ++i) {
                    const int v = t + 512 * i, pl = v >> 10, vp = v & 1023;
                    const int n = vp >> 2, sg = (vp & 3) << 3;
                    wv[i] = *(const bf16x8*)((pl ? W2l : W2h) + (size_t)n * H_DIM + k0 + 32 + sg);
                }
            }
            bf16x8 a0h = *(const bf16x8*)(&E1h[m16 * LDE + k0 + quad * 8]);
            bf16x8 a0l = *(const bf16x8*)(&E1l[m16 * LDE + k0 + quad * 8]);
            bf16x8 a1h = *(const bf16x8*)(&E1h[(16 + m16) * LDE + k0 + quad * 8]);
            bf16x8 a1l = *(const bf16x8*)(&E1l[(16 + m16) * LDE + k0 + quad * 8]);
            #pragma unroll
            for (int jj = 0; jj < 2; ++jj) {
                const int bn = (32 * w + jj * 16 + m16) * LDW + quad * 8;
                bf16x8 b_h = *(const bf16x8*)(&Bsh[bn]);
                bf16x8 b_l = *(const bf16x8*)(&Bsl[bn]);
                acc[0][jj] = __builtin_amdgcn_mfma_f32_16x16x32_bf16(a0h, b_h, acc[0][jj], 0, 0, 0);
                acc[0][jj] = __builtin_amdgcn_mfma_f32_16x16x32_bf16(a0l, b_h, acc[0][jj], 0, 0, 0);
                acc[0][jj] = __builtin_amdgcn_mfma_f32_16x16x32_bf16(a0h, b_l, acc[0][jj], 0, 0, 0);
                acc[1][jj] = __builtin_amdgcn_mfma_f32_16x16x32_bf16(a1h, b_h, acc[1][jj], 0, 0, 0);
                acc[1][jj] = __builtin_amdgcn_mfma_f32_16x16x32_bf16(a1l, b_h, acc[1][jj], 0, 0, 0);
                acc[1][jj] = __builtin_amdgcn_mfma_f32_16x16x32_bf16(a1h, b_l, acc[1][jj], 0, 0, 0);
            }
        }
        #pragma unroll
        for (int i = 0; i < 2; ++i)
            #pragma unroll
            for (int jj = 0; jj < 2; ++jj) {
                const int c = 32 * w + jj * 16 + m16;
                const float bv = b2[c];
                #pragma unroll
                for (int r = 0; r < 4; ++r) {
                    const int rr = i * 16 + quad * 4 + r;
                    float vv = fmaxf(acc[i][jj][r] + bv, 0.0f);
                    split2(vv, E2h[rr * LDE + c], E2l[rr * LDE + c]);
                }
            }
    }

    // ====== GEMM3 + tanh + colsum + dot(Wh): atomicAdd one scalar ======
    {
        const int rf = w >> 2, cf = w & 3;
        f32x4 acc3 = {0.f, 0.f, 0.f, 0.f};
        const int pl = t >> 8, n = (t & 255) >> 2, sg = (t & 3) << 3;
        bf16x8 wq = *(const bf16x8*)((pl ? Wql : Wqh) + (size_t)n * H_DIM + sg);
        for (int k0 = 0; k0 < H_DIM; k0 += 32) {
            __syncthreads();     // also orders E2 writes before E2 reads
            *(bf16x8*)&(pl ? Bsl : Bsh)[n * LDW + sg] = wq;
            __syncthreads();
            if (k0 + 32 < H_DIM)
                wq = *(const bf16x8*)((pl ? Wql : Wqh) + (size_t)n * H_DIM + k0 + 32 + sg);
            bf16x8 a_h = *(const bf16x8*)(&E2h[(rf * 16 + m16) * LDE + k0 + quad * 8]);
            bf16x8 a_l = *(const bf16x8*)(&E2l[(rf * 16 + m16) * LDE + k0 + quad * 8]);
            const int bn = (cf * 16 + m16) * LDW + quad * 8;
            bf16x8 b_h = *(const bf16x8*)(&Bsh[bn]);
            bf16x8 b_l = *(const bf16x8*)(&Bsl[bn]);
            acc3 = __builtin_amdgcn_mfma_f32_16x16x32_bf16(a_h, b_h, acc3, 0, 0, 0);
            acc3 = __builtin_amdgcn_mfma_f32_16x16x32_bf16(a_l, b_h, acc3, 0, 0, 0);
            acc3 = __builtin_amdgcn_mfma_f32_16x16x32_bf16(a_h, b_l, acc3, 0, 0, 0);
        }
        const int c = cf * 16 + m16;
        const float bv = bq[c];
        float v = 0.f;
        #pragma unroll
        for (int r = 0; r < 4; ++r)
            v += tanhf(acc3[r] + bv);
        v += __shfl_xor(v, 16, 64);       // sum rows within row-frag
        v += __shfl_xor(v, 32, 64);
        if (quad == 0) red[rf][c] = v;    // (rf,cf) waves write disjoint cols
        __syncthreads();
        if (t < W_DIM) {
            float s = (red[0][t] + red[1][t]) * Wh[t];
            #pragma unroll
            for (int o = 32; o > 0; o >>= 1) s += __shfl_down(s, o);
            if (t == 0) atomicAdd(out, s);
        }
    }
}

extern "C" void kernel_launch(void* const* d_in, const int* in_sizes, int n_in,
                              void* d_out, int out_size, void* d_ws, size_t ws_size,
                              hipStream_t stream) {
    const float* state = (const float*)d_in[0];
    const float* W1    = (const float*)d_in[1];
    const float* b1    = (const float*)d_in[2];
    const float* W2    = (const float*)d_in[3];
    const float* b2    = (const float*)d_in[4];
    const float* Wq    = (const float*)d_in[5];
    const float* bq    = (const float*)d_in[6];
    const float* Wh    = (const float*)d_in[7];
    const float* bh    = (const float*)d_in[8];

    bf16* p = (bf16*)d_ws;
    bf16* W1h = p; p += (size_t)H_DIM * F_IN;
    bf16* W1l = p; p += (size_t)H_DIM * F_IN;
    bf16* W2h = p; p += (size_t)H_DIM * H_DIM;
    bf16* W2l = p; p += (size_t)H_DIM * H_DIM;
    bf16* Wqh = p; p += (size_t)W_DIM * H_DIM;
    bf16* Wql = p; p += (size_t)W_DIM * H_DIM;

    prep_w<<<W_BLOCKS, 256, 0, stream>>>(
        W1, W2, Wq, bh, W1h, W1l, W2h, W2l, Wqh, Wql, (float*)d_out);

    fused_chain<<<N_ROWS / 32, 512, 0, stream>>>(
        state, W1h, W1l, W2h, W2l, Wqh, Wql, b1, b2, bq, Wh, (float*)d_out);
}

// Round 7
// 103.820 us; speedup vs baseline: 1.4052x; 1.0247x over previous
//
#include <hip/hip_runtime.h>
#include <hip/hip_bf16.h>
#include <math.h>

// out = colsum( tanh( relu( relu(S@W1+b1)@W2+b2 )@Wq+bq ) ) @ Wh + bh
// (graph stage is a no-op: all edge weights 1.0 => mean_w == 1.0 everywhere)
//
// Round 7: fused chain (32-row strip per block, E1/E2 in LDS, split-bf16
// MFMA) with BK=64 weight staging -> barrier count 80 -> 32. At 1 block/CU
// every __syncthreads drain is unhidden; fewer, fatter rounds amortize it.

#define N_ROWS 8192
#define F_IN   512
#define H_DIM  256
#define W_DIM  64

#define LDW 72    // staging leading dim (bf16): 144 B stride -> 2-way (free)
#define LDE 280   // E-plane leading dim: 560 B stride -> 2-way (free)

#define W1_E (F_IN * H_DIM)
#define W2_E (H_DIM * H_DIM)
#define WQ_E (H_DIM * W_DIM)
#define W_BLOCKS ((W1_E + W2_E + WQ_E + 255) / 256)

using bf16x8 = __attribute__((ext_vector_type(8))) short;
using bf16x4 = __attribute__((ext_vector_type(4))) short;
using f32x4  = __attribute__((ext_vector_type(4))) float;
typedef __hip_bfloat16 bf16;

__device__ __forceinline__ void split2(float v, bf16& hi, bf16& lo) {
    bf16 h = __float2bfloat16(v);
    hi = h;
    lo = __float2bfloat16(v - __bfloat162float(h));
}

// ---- weight split+transpose: W[K][N] fp32 -> hi/lo [N][K] bf16; out = bh ----
__global__ __launch_bounds__(256) void prep_w(
    const float* __restrict__ W1, const float* __restrict__ W2,
    const float* __restrict__ Wq, const float* __restrict__ bh,
    bf16* __restrict__ W1h, bf16* __restrict__ W1l,
    bf16* __restrict__ W2h, bf16* __restrict__ W2l,
    bf16* __restrict__ Wqh, bf16* __restrict__ Wql,
    float* __restrict__ out)
{
    if (blockIdx.x == 0 && threadIdx.x == 0) out[0] = bh[0];
    int gid = blockIdx.x * 256 + threadIdx.x;
    if (gid < W1_E) {                       // W1 [512][256] -> [256][512]
        int k = gid >> 8, n = gid & 255;
        split2(W1[gid], W1h[n * F_IN + k], W1l[n * F_IN + k]);
        return;
    }
    gid -= W1_E;
    if (gid < W2_E) {                       // W2 [256][256] -> [256][256]
        int k = gid >> 8, n = gid & 255;
        split2(W2[gid], W2h[n * H_DIM + k], W2l[n * H_DIM + k]);
        return;
    }
    gid -= W2_E;
    if (gid < WQ_E) {                       // Wq [256][64] -> [64][256]
        int k = gid >> 6, n = gid & 63;
        split2(Wq[gid], Wqh[n * H_DIM + k], Wql[n * H_DIM + k]);
    }
}

// ---- fused: 32-row strip, whole chain in one block, BK=64 staging ----
// 512 threads = 8 waves. gemm1/2: wave w -> cols 32w..32w+32 (2 col-frags)
// x 2 row-frags. gemm3: wave w -> row-frag w>>2, col-frag w&3.
__global__ __launch_bounds__(512) void fused_chain(
    const float* __restrict__ S,
    const bf16* __restrict__ W1h, const bf16* __restrict__ W1l,
    const bf16* __restrict__ W2h, const bf16* __restrict__ W2l,
    const bf16* __restrict__ Wqh, const bf16* __restrict__ Wql,
    const float* __restrict__ b1, const float* __restrict__ b2,
    const float* __restrict__ bq, const float* __restrict__ Wh,
    float* __restrict__ out)
{
    __shared__ bf16 Ssh[32 * LDW];          // 32 rows x 64 k
    __shared__ bf16 Ssl[32 * LDW];
    __shared__ bf16 Bsh[256 * LDW];         // 256 n x 64 k
    __shared__ bf16 Bsl[256 * LDW];
    __shared__ bf16 E1h[32 * LDE];
    __shared__ bf16 E1l[32 * LDE];
    __shared__ bf16 E2h[32 * LDE];
    __shared__ bf16 E2l[32 * LDE];
    __shared__ float red[2][64];

    const int t = threadIdx.x;
    const int w = t >> 6, quad = (t & 63) >> 4, m16 = t & 15;
    const int row0 = blockIdx.x * 32;

    // ================= GEMM1: E1 = relu(S @ W1^T + b1) =================
    f32x4 acc[2][2] = {};
    {
        const int srow = t >> 4, scol = (t & 15) << 2;   // 4 fp32 per thread
        float4 sv;
        bf16x8 wv[8];
        sv = *(const float4*)(S + (size_t)(row0 + srow) * F_IN + scol);
        #pragma unroll
        for (int i = 0; i < 8; ++i) {        // Bs: 256n x 64k x 2 planes
            const int c = t + 512 * i, pl = c >> 11, cp = c & 2047;
            const int n = cp >> 3, sg = (cp & 7) << 3;
            wv[i] = *(const bf16x8*)((pl ? W1l : W1h) + (size_t)n * F_IN + sg);
        }
        for (int k0 = 0; k0 < F_IN; k0 += 64) {
            __syncthreads();
            {
                bf16 hb[4], lb[4];
                split2(sv.x, hb[0], lb[0]); split2(sv.y, hb[1], lb[1]);
                split2(sv.z, hb[2], lb[2]); split2(sv.w, hb[3], lb[3]);
                *(bf16x4*)&Ssh[srow * LDW + scol] = *(const bf16x4*)hb;
                *(bf16x4*)&Ssl[srow * LDW + scol] = *(const bf16x4*)lb;
            }
            #pragma unroll
            for (int i = 0; i < 8; ++i) {
                const int c = t + 512 * i, pl = c >> 11, cp = c & 2047;
                const int n = cp >> 3, sg = (cp & 7) << 3;
                *(bf16x8*)&(pl ? Bsl : Bsh)[n * LDW + sg] = wv[i];
            }
            __syncthreads();
            if (k0 + 64 < F_IN) {            // prefetch next 64-k tile
                sv = *(const float4*)(S + (size_t)(row0 + srow) * F_IN + k0 + 64 + scol);
                #pragma unroll
                for (int i = 0; i < 8; ++i) {
                    const int c = t + 512 * i, pl = c >> 11, cp = c & 2047;
                    const int n = cp >> 3, sg = (cp & 7) << 3;
                    wv[i] = *(const bf16x8*)((pl ? W1l : W1h) + (size_t)n * F_IN + k0 + 64 + sg);
                }
            }
            #pragma unroll
            for (int kk = 0; kk < 64; kk += 32) {
                bf16x8 a0h = *(const bf16x8*)(&Ssh[m16 * LDW + kk + quad * 8]);
                bf16x8 a0l = *(const bf16x8*)(&Ssl[m16 * LDW + kk + quad * 8]);
                bf16x8 a1h = *(const bf16x8*)(&Ssh[(16 + m16) * LDW + kk + quad * 8]);
                bf16x8 a1l = *(const bf16x8*)(&Ssl[(16 + m16) * LDW + kk + quad * 8]);
                #pragma unroll
                for (int jj = 0; jj < 2; ++jj) {
                    const int bn = (32 * w + jj * 16 + m16) * LDW + kk + quad * 8;
                    bf16x8 b_h = *(const bf16x8*)(&Bsh[bn]);
                    bf16x8 b_l = *(const bf16x8*)(&Bsl[bn]);
                    acc[0][jj] = __builtin_amdgcn_mfma_f32_16x16x32_bf16(a0h, b_h, acc[0][jj], 0, 0, 0);
                    acc[0][jj] = __builtin_amdgcn_mfma_f32_16x16x32_bf16(a0l, b_h, acc[0][jj], 0, 0, 0);
                    acc[0][jj] = __builtin_amdgcn_mfma_f32_16x16x32_bf16(a0h, b_l, acc[0][jj], 0, 0, 0);
                    acc[1][jj] = __builtin_amdgcn_mfma_f32_16x16x32_bf16(a1h, b_h, acc[1][jj], 0, 0, 0);
                    acc[1][jj] = __builtin_amdgcn_mfma_f32_16x16x32_bf16(a1l, b_h, acc[1][jj], 0, 0, 0);
                    acc[1][jj] = __builtin_amdgcn_mfma_f32_16x16x32_bf16(a1h, b_l, acc[1][jj], 0, 0, 0);
                }
            }
        }
        // epilogue: relu + bias -> E1 hi/lo (LDS)
        #pragma unroll
        for (int i = 0; i < 2; ++i)
            #pragma unroll
            for (int jj = 0; jj < 2; ++jj) {
                const int c = 32 * w + jj * 16 + m16;
                const float bv = b1[c];
                #pragma unroll
                for (int r = 0; r < 4; ++r) {
                    const int rr = i * 16 + quad * 4 + r;
                    float vv = fmaxf(acc[i][jj][r] + bv, 0.0f);
                    split2(vv, E1h[rr * LDE + c], E1l[rr * LDE + c]);
                }
            }
    }

    // ================= GEMM2: E2 = relu(E1 @ W2^T + b2) =================
    {
        bf16x8 wv[8];
        #pragma unroll
        for (int i = 0; i < 8; ++i) {
            const int c = t + 512 * i, pl = c >> 11, cp = c & 2047;
            const int n = cp >> 3, sg = (cp & 7) << 3;
            wv[i] = *(const bf16x8*)((pl ? W2l : W2h) + (size_t)n * H_DIM + sg);
        }
        #pragma unroll
        for (int i = 0; i < 2; ++i)
            #pragma unroll
            for (int jj = 0; jj < 2; ++jj)
                acc[i][jj] = (f32x4){0.f, 0.f, 0.f, 0.f};
        for (int k0 = 0; k0 < H_DIM; k0 += 64) {
            __syncthreads();     // also orders E1 writes before E1 reads
            #pragma unroll
            for (int i = 0; i < 8; ++i) {
                const int c = t + 512 * i, pl = c >> 11, cp = c & 2047;
                const int n = cp >> 3, sg = (cp & 7) << 3;
                *(bf16x8*)&(pl ? Bsl : Bsh)[n * LDW + sg] = wv[i];
            }
            __syncthreads();
            if (k0 + 64 < H_DIM) {
                #pragma unroll
                for (int i = 0; i < 8; ++i) {
                    const int c = t + 512 * i, pl = c >> 11, cp = c & 2047;
                    const int n = cp >> 3, sg = (cp & 7) << 3;
                    wv[i] = *(const bf16x8*)((pl ? W2l : W2h) + (size_t)n * H_DIM + k0 + 64 + sg);
                }
            }
            #pragma unroll
            for (int kk = 0; kk < 64; kk += 32) {
                bf16x8 a0h = *(const bf16x8*)(&E1h[m16 * LDE + k0 + kk + quad * 8]);
                bf16x8 a0l = *(const bf16x8*)(&E1l[m16 * LDE + k0 + kk + quad * 8]);
                bf16x8 a1h = *(const bf16x8*)(&E1h[(16 + m16) * LDE + k0 + kk + quad * 8]);
                bf16x8 a1l = *(const bf16x8*)(&E1l[(16 + m16) * LDE + k0 + kk + quad * 8]);
                #pragma unroll
                for (int jj = 0; jj < 2; ++jj) {
                    const int bn = (32 * w + jj * 16 + m16) * LDW + kk + quad * 8;
                    bf16x8 b_h = *(const bf16x8*)(&Bsh[bn]);
                    bf16x8 b_l = *(const bf16x8*)(&Bsl[bn]);
                    acc[0][jj] = __builtin_amdgcn_mfma_f32_16x16x32_bf16(a0h, b_h, acc[0][jj], 0, 0, 0);
                    acc[0][jj] = __builtin_amdgcn_mfma_f32_16x16x32_bf16(a0l, b_h, acc[0][jj], 0, 0, 0);
                    acc[0][jj] = __builtin_amdgcn_mfma_f32_16x16x32_bf16(a0h, b_l, acc[0][jj], 0, 0, 0);
                    acc[1][jj] = __builtin_amdgcn_mfma_f32_16x16x32_bf16(a1h, b_h, acc[1][jj], 0, 0, 0);
                    acc[1][jj] = __builtin_amdgcn_mfma_f32_16x16x32_bf16(a1l, b_h, acc[1][jj], 0, 0, 0);
                    acc[1][jj] = __builtin_amdgcn_mfma_f32_16x16x32_bf16(a1h, b_l, acc[1][jj], 0, 0, 0);
                }
            }
        }
        #pragma unroll
        for (int i = 0; i < 2; ++i)
            #pragma unroll
            for (int jj = 0; jj < 2; ++jj) {
                const int c = 32 * w + jj * 16 + m16;
                const float bv = b2[c];
                #pragma unroll
                for (int r = 0; r < 4; ++r) {
                    const int rr = i * 16 + quad * 4 + r;
                    float vv = fmaxf(acc[i][jj][r] + bv, 0.0f);
                    split2(vv, E2h[rr * LDE + c], E2l[rr * LDE + c]);
                }
            }
    }

    // ====== GEMM3 + tanh + colsum + dot(Wh): atomicAdd one scalar ======
    {
        const int rf = w >> 2, cf = w & 3;
        f32x4 acc3 = {0.f, 0.f, 0.f, 0.f};
        bf16x8 wq[2];
        #pragma unroll
        for (int i = 0; i < 2; ++i) {        // Bs: 64n x 64k x 2 planes
            const int c = t + 512 * i, pl = c >> 9, cp = c & 511;
            const int n = cp >> 3, sg = (cp & 7) << 3;
            wq[i] = *(const bf16x8*)((pl ? Wql : Wqh) + (size_t)n * H_DIM + sg);
        }
        for (int k0 = 0; k0 < H_DIM; k0 += 64) {
            __syncthreads();     // also orders E2 writes before E2 reads
            #pragma unroll
            for (int i = 0; i < 2; ++i) {
                const int c = t + 512 * i, pl = c >> 9, cp = c & 511;
                const int n = cp >> 3, sg = (cp & 7) << 3;
                *(bf16x8*)&(pl ? Bsl : Bsh)[n * LDW + sg] = wq[i];
            }
            __syncthreads();
            if (k0 + 64 < H_DIM) {
                #pragma unroll
                for (int i = 0; i < 2; ++i) {
                    const int c = t + 512 * i, pl = c >> 9, cp = c & 511;
                    const int n = cp >> 3, sg = (cp & 7) << 3;
                    wq[i] = *(const bf16x8*)((pl ? Wql : Wqh) + (size_t)n * H_DIM + k0 + 64 + sg);
                }
            }
            #pragma unroll
            for (int kk = 0; kk < 64; kk += 32) {
                bf16x8 a_h = *(const bf16x8*)(&E2h[(rf * 16 + m16) * LDE + k0 + kk + quad * 8]);
                bf16x8 a_l = *(const bf16x8*)(&E2l[(rf * 16 + m16) * LDE + k0 + kk + quad * 8]);
                const int bn = (cf * 16 + m16) * LDW + kk + quad * 8;
                bf16x8 b_h = *(const bf16x8*)(&Bsh[bn]);
                bf16x8 b_l = *(const bf16x8*)(&Bsl[bn]);
                acc3 = __builtin_amdgcn_mfma_f32_16x16x32_bf16(a_h, b_h, acc3, 0, 0, 0);
                acc3 = __builtin_amdgcn_mfma_f32_16x16x32_bf16(a_l, b_h, acc3, 0, 0, 0);
                acc3 = __builtin_amdgcn_mfma_f32_16x16x32_bf16(a_h, b_l, acc3, 0, 0, 0);
            }
        }
        const int c = cf * 16 + m16;
        const float bv = bq[c];
        float v = 0.f;
        #pragma unroll
        for (int r = 0; r < 4; ++r)
            v += tanhf(acc3[r] + bv);
        v += __shfl_xor(v, 16, 64);       // sum rows within row-frag
        v += __shfl_xor(v, 32, 64);
        if (quad == 0) red[rf][c] = v;    // (rf,cf) waves write disjoint cols
        __syncthreads();
        if (t < W_DIM) {
            float s = (red[0][t] + red[1][t]) * Wh[t];
            #pragma unroll
            for (int o = 32; o > 0; o >>= 1) s += __shfl_down(s, o);
            if (t == 0) atomicAdd(out, s);
        }
    }
}

extern "C" void kernel_launch(void* const* d_in, const int* in_sizes, int n_in,
                              void* d_out, int out_size, void* d_ws, size_t ws_size,
                              hipStream_t stream) {
    const float* state = (const float*)d_in[0];
    const float* W1    = (const float*)d_in[1];
    const float* b1    = (const float*)d_in[2];
    const float* W2    = (const float*)d_in[3];
    const float* b2    = (const float*)d_in[4];
    const float* Wq    = (const float*)d_in[5];
    const float* bq    = (const float*)d_in[6];
    const float* Wh    = (const float*)d_in[7];
    const float* bh    = (const float*)d_in[8];

    bf16* p = (bf16*)d_ws;
    bf16* W1h = p; p += (size_t)H_DIM * F_IN;
    bf16* W1l = p; p += (size_t)H_DIM * F_IN;
    bf16* W2h = p; p += (size_t)H_DIM * H_DIM;
    bf16* W2l = p; p += (size_t)H_DIM * H_DIM;
    bf16* Wqh = p; p += (size_t)W_DIM * H_DIM;
    bf16* Wql = p; p += (size_t)W_DIM * H_DIM;

    prep_w<<<W_BLOCKS, 256, 0, stream>>>(
        W1, W2, Wq, bh, W1h, W1l, W2h, W2l, Wqh, Wql, (float*)d_out);

    fused_chain<<<N_ROWS / 32, 512, 0, stream>>>(
        state, W1h, W1l, W2h, W2l, Wqh, Wql, b1, b2, bq, Wh, (float*)d_out);
}